// Round 4
// baseline (345.187 us; speedup 1.0000x reference)
//
#include <hip/hip_runtime.h>
#include <hip/hip_bf16.h>
#include <math.h>

#define V 32000
#define E 512
#define H 512
#define N 64
#define L 128
#define NV (N*V)
#define NH (N*H)
#define MTOT (N*L)   // 8192 rows of the score GEMM
#define VT 500       // v-tiles (of 64) in k_logits

typedef short  s8v  __attribute__((ext_vector_type(8)));   // 8 bf16 (4 VGPRs)
typedef float  f4v  __attribute__((ext_vector_type(4)));

__device__ __forceinline__ float sigf(float x) { return 1.0f / (1.0f + __expf(-x)); }

// fp32 -> bf16 round-to-nearest-even (scalar path, non-hot kernels)
__device__ __forceinline__ unsigned short f2bf(float f) {
    unsigned int u = __float_as_uint(f);
    unsigned int r = u + 0x7FFFu + ((u >> 16) & 1u);
    return (unsigned short)(r >> 16);
}

// pair fp32 -> packed 2xbf16, RNE; compiler emits v_cvt_pk_bf16_f32
__device__ __forceinline__ unsigned int cvt2bf(float x, float y) {
    __hip_bfloat162 h2 = __float22bfloat162_rn(make_float2(x, y));
    unsigned int r;
    __builtin_memcpy(&r, &h2, 4);
    return r;
}

// 8 fp32 -> 4 packed bf16 pairs (one 16B LDS store)
__device__ __forceinline__ uint4 pack_q(float4 lo, float4 hi) {
    uint4 q;
    q.x = cvt2bf(lo.x, lo.y); q.y = cvt2bf(lo.z, lo.w);
    q.z = cvt2bf(hi.x, hi.y); q.w = cvt2bf(hi.z, hi.w);
    return q;
}

// ---------------------------------------------------------------------------
// K1: LSTM gate GEMM, k-split partials. grid (32 j-tiles, 8 k-splits of 128),
// block 256. v2 tiling: each thread owns 4 n x 4 j -> per e4-step only
// 4 broadcast LDS reads + 4 global w reads feed 16 FMA4 (was 16 LDS + 1
// global). LDS instrs/thread 512 -> 128 (issue-bound fix). xs padded to
// 132 floats/row (33 float4) to spread nq rows across bank quads.
// ---------------------------------------------------------------------------
__global__ __launch_bounds__(256) void k_gates(
    const int* __restrict__ ids, const float* __restrict__ hprev,
    const float* __restrict__ embW, const float* __restrict__ w_ih,
    const float* __restrict__ w_hh, float* __restrict__ gates_p)
{
    __shared__ __align__(16) float xs[64 * 132];  // 33 KB
    const int bx = blockIdx.x;   // j-tile
    const int ks = blockIdx.y;   // k-split (0..7): 0-3 emb, 4-7 h
    const int tid = threadIdx.x;
    const bool emb_part = (ks < 4);
    const int koff = (ks & 3) * 128;

    for (int i = tid; i < 64 * 32; i += 256) {
        int n = i >> 5, kk4 = i & 31;
        float4 x4;
        if (emb_part)
            x4 = ((const float4*)(embW + (size_t)ids[n] * E + koff))[kk4];
        else
            x4 = ((const float4*)(hprev + (size_t)n * H + koff))[kk4];
        ((float4*)xs)[n * 33 + kk4] = x4;
    }
    __syncthreads();

    const int jq = tid & 15;          // owns j0..j0+3
    const int nq = tid >> 4;          // owns n0..n0+3
    const int j0 = jq * 4;
    const int n0 = nq * 4;
    const float* wbase = (emb_part ? w_ih : w_hh)
                       + (size_t)(bx * 64 + j0) * 512 + koff;

    float acc[4][4];
#pragma unroll
    for (int nn = 0; nn < 4; ++nn)
#pragma unroll
        for (int jj = 0; jj < 4; ++jj) acc[nn][jj] = 0.f;

    for (int e4 = 0; e4 < 32; ++e4) {
        float4 w4[4];
#pragma unroll
        for (int jj = 0; jj < 4; ++jj)
            w4[jj] = ((const float4*)(wbase + (size_t)jj * 512))[e4];
        float4 x4[4];
#pragma unroll
        for (int nn = 0; nn < 4; ++nn)
            x4[nn] = ((const float4*)xs)[(n0 + nn) * 33 + e4];   // broadcast
#pragma unroll
        for (int nn = 0; nn < 4; ++nn)
#pragma unroll
            for (int jj = 0; jj < 4; ++jj)
                acc[nn][jj] += w4[jj].x * x4[nn].x + w4[jj].y * x4[nn].y
                             + w4[jj].z * x4[nn].z + w4[jj].w * x4[nn].w;
    }
#pragma unroll
    for (int nn = 0; nn < 4; ++nn) {
        float4 o = make_float4(acc[nn][0], acc[nn][1], acc[nn][2], acc[nn][3]);
        *(float4*)(gates_p + (size_t)ks * (64 * 2048)
                 + (size_t)(n0 + nn) * 2048 + bx * 64 + j0) = o;
    }
}

// ---------------------------------------------------------------------------
// K1b: combine partials + biases, LSTM pointwise.  (unchanged)
// ---------------------------------------------------------------------------
__global__ __launch_bounds__(256) void k_lstm_pw(
    const float* __restrict__ gates_p, const float* __restrict__ b_ih,
    const float* __restrict__ b_hh, const float* __restrict__ cprev,
    float* __restrict__ out, unsigned short* __restrict__ xb)
{
    int i = blockIdx.x * 256 + threadIdx.x;  // 0..32767
    if (i >= NH) return;
    int n = i >> 9, k = i & 511;
    float g[4];
#pragma unroll
    for (int q = 0; q < 4; ++q) {
        int j = q * 512 + k;
        float s = b_ih[j] + b_hh[j];
#pragma unroll
        for (int ks = 0; ks < 8; ++ks)
            s += gates_p[(size_t)ks * (64 * 2048) + (size_t)n * 2048 + j];
        g[q] = s;
    }
    float ig = sigf(g[0]), fg = sigf(g[1]), gg = tanhf(g[2]), og = sigf(g[3]);
    float ct = fg * cprev[i] + ig * gg;
    float ht = og * tanhf(ct);
    out[NV + i] = ht;
    out[NV + NH + i] = ct;
    xb[(size_t)n * 1024 + k] = f2bf(ht);
}

// ---------------------------------------------------------------------------
// K2a: sproj = h_t @ Wh.T  (64 x 512, K=512). grid 128, block 256. (unchanged)
// ---------------------------------------------------------------------------
__global__ __launch_bounds__(256) void k_sproj(
    const float* __restrict__ out, const float* __restrict__ Wh,
    float* __restrict__ sproj)
{
    __shared__ __align__(16) float xs[512];
    int n = blockIdx.x >> 1;
    int h = (blockIdx.x & 1) * 256 + threadIdx.x;
    const float* ht = out + NV + (size_t)n * 512;
    for (int i = threadIdx.x; i < 512; i += 256) xs[i] = ht[i];
    __syncthreads();
    const float* wrow = Wh + (size_t)h * 512;
    float acc = 0.f;
    for (int e4 = 0; e4 < 128; ++e4) {
        float4 w4 = ((const float4*)wrow)[e4];
        float4 x4 = ((const float4*)xs)[e4];
        acc += w4.x * x4.x + w4.y * x4.y + w4.z * x4.z + w4.w * x4.w;
    }
    sproj[(size_t)n * 512 + h] = acc;
}

// ---------------------------------------------------------------------------
// K2b: score GEMM via bf16 MFMA + fused tanh/v-dot epilogue. Grid (8 bh,
// 128 bm), bh fastest for enc L2/L3 locality.  (R3 verbatim)
// ---------------------------------------------------------------------------
__global__ __launch_bounds__(256) void k_score_gemm(
    const float* __restrict__ enc, const float* __restrict__ Ws,
    const float* __restrict__ sproj, const float* __restrict__ av,
    float* __restrict__ scorep)
{
    __shared__ __align__(16) short As[64 * 72];
    __shared__ __align__(16) short Bs[64 * 72];
    __shared__ float sred[64];

    const int bh = blockIdx.x, bm = blockIdx.y;   // bh fastest-varying
    const int tid = threadIdx.x;
    const int w = tid >> 6, l = tid & 63;
    const int wave_m = (w >> 1) * 32, wave_h = (w & 1) * 32;
    const int lq = l >> 4, lr = l & 15;

    if (tid < 64) sred[tid] = 0.f;

    f4v acc[2][2];
#pragma unroll
    for (int i = 0; i < 2; ++i)
#pragma unroll
        for (int j = 0; j < 2; ++j) acc[i][j] = (f4v)0.f;

    for (int kt = 0; kt < 8; ++kt) {
        __syncthreads();
#pragma unroll
        for (int r = 0; r < 2; ++r) {
            int idx = (r * 256 + tid) * 8;
            int row = idx >> 6, col = idx & 63;
            const float* sa = enc + (size_t)(bm * 64 + row) * 512 + kt * 64 + col;
            const float* sb = Ws  + (size_t)(bh * 64 + row) * 512 + kt * 64 + col;
            float4 a0 = *(const float4*)sa, a1 = *(const float4*)(sa + 4);
            float4 b0 = *(const float4*)sb, b1 = *(const float4*)(sb + 4);
            *(uint4*)(As + row * 72 + col) = pack_q(a0, a1);
            *(uint4*)(Bs + row * 72 + col) = pack_q(b0, b1);
        }
        __syncthreads();

#pragma unroll
        for (int ks = 0; ks < 2; ++ks) {
            s8v a_frag[2], b_frag[2];
#pragma unroll
            for (int i = 0; i < 2; ++i)
                a_frag[i] = *(const s8v*)(As + (wave_m + 16 * i + lr) * 72 + ks * 32 + lq * 8);
#pragma unroll
            for (int j = 0; j < 2; ++j)
                b_frag[j] = *(const s8v*)(Bs + (wave_h + 16 * j + lr) * 72 + ks * 32 + lq * 8);
#pragma unroll
            for (int i = 0; i < 2; ++i)
#pragma unroll
                for (int j = 0; j < 2; ++j)
                    acc[i][j] = __builtin_amdgcn_mfma_f32_16x16x32_bf16(
                        a_frag[i], b_frag[j], acc[i][j], 0, 0, 0);
        }
    }
    __syncthreads();

    const int hc0 = bh * 64 + wave_h + lr;
#pragma unroll
    for (int i = 0; i < 2; ++i) {
#pragma unroll
        for (int reg = 0; reg < 4; ++reg) {
            int m_local = wave_m + 16 * i + lq * 4 + reg;
            int m = bm * 64 + m_local;
            int n = m >> 7;
            float p = 0.f;
#pragma unroll
            for (int j = 0; j < 2; ++j) {
                int hc = hc0 + 16 * j;
                float val = acc[i][j][reg] + sproj[(size_t)n * 512 + hc];
                p += tanhf(val) * av[hc];
            }
            p += __shfl_xor(p, 1, 64);
            p += __shfl_xor(p, 2, 64);
            p += __shfl_xor(p, 4, 64);
            p += __shfl_xor(p, 8, 64);
            if (lr == 0) atomicAdd(&sred[m_local], p);
        }
    }
    __syncthreads();
    if (tid < 64)
        scorep[(size_t)bh * MTOT + bm * 64 + tid] = sred[tid];
}

// ---------------------------------------------------------------------------
// K2c: combine score partials, mask, softmax over L, context. 4-way split
// over H. grid (64 n, 4 h-chunks), block 128.  (R3 verbatim)
// ---------------------------------------------------------------------------
__global__ __launch_bounds__(128) void k_softmax_ctx(
    const float* __restrict__ scorep, const unsigned char* __restrict__ mask,
    const float* __restrict__ enc, unsigned short* __restrict__ xb)
{
    __shared__ float wl[128];
    __shared__ float red[4];
    const int n = blockIdx.x, hc = blockIdx.y, t = threadIdx.x;  // t = l index

    float s = 0.f;
#pragma unroll
    for (int q = 0; q < 8; ++q)
        s += scorep[(size_t)q * MTOT + n * 128 + t];
    if (mask[(size_t)n * 128 + t]) s = -1e30f;

    float m = s;
#pragma unroll
    for (int off = 32; off > 0; off >>= 1) m = fmaxf(m, __shfl_xor(m, off, 64));
    if ((t & 63) == 0) red[t >> 6] = m;
    __syncthreads();
    m = fmaxf(red[0], red[1]);
    float e = __expf(s - m);
    float ss = e;
#pragma unroll
    for (int off = 32; off > 0; off >>= 1) ss += __shfl_xor(ss, off, 64);
    if ((t & 63) == 0) red[2 + (t >> 6)] = ss;
    __syncthreads();
    float inv = 1.0f / (red[2] + red[3]);
    wl[t] = e * inv;
    __syncthreads();

    const float* encn = enc + (size_t)n * (L * H) + hc * 128 + t;
    float acc = 0.f;
#pragma unroll 8
    for (int ll = 0; ll < 128; ++ll)
        acc += wl[ll] * encn[(size_t)ll * 512];
    xb[(size_t)n * 1024 + 512 + hc * 128 + t] = f2bf(acc);
}

// ---------------------------------------------------------------------------
// K4a: logits GEMM via bf16 MFMA. v3 (R3 verbatim): 512 threads = 8 waves,
// in-block K-split (waves 0-3: K[0:512], waves 4-7: K[512:1024]), halves
// combined through the cs transpose buffer. Epilogue threads 0-255.
// ---------------------------------------------------------------------------
__global__ __launch_bounds__(512) void k_logits(
    const float* __restrict__ h2oW, const unsigned short* __restrict__ xb,
    const float* __restrict__ h2ob, float* __restrict__ dlogits,
    float* __restrict__ pmax, float* __restrict__ psum)
{
    __shared__ __align__(16) short As[2][64 * 72];   // 18432 B
    __shared__ __align__(16) short Bs[2][64 * 72];   // 18432 B
    __shared__ __align__(16) float cs[64 * 68];      // 17408 B

    const int bm = blockIdx.x;   // v-tile
    const int tid = threadIdx.x;
    const int g = tid >> 8;            // K-half (0 or 1)
    const int tl = tid & 255;          // index within group
    const int w2 = (tid >> 6) & 3;     // wave within group
    const int l = tid & 63;
    const int wave_m = (w2 & 1) * 32, wave_n = (w2 >> 1) * 32;
    const int lq = l >> 4, lr = l & 15;

    const int arow = tl >> 2;            // 0..63
    const int acol = (tl & 3) * 16;      // 0,16,32,48
    const float* aptr = h2oW + (size_t)(bm * 64 + arow) * 1024 + g * 512 + acol;
    const unsigned short* bptr = xb + (size_t)arow * 1024 + g * 512 + acol;

    short* Asg = As[g];
    short* Bsg = Bs[g];

    f4v acc[2][2];
#pragma unroll
    for (int i = 0; i < 2; ++i)
#pragma unroll
        for (int j = 0; j < 2; ++j) acc[i][j] = (f4v)0.f;

#pragma unroll 1
    for (int kt = 0; kt < 8; ++kt) {
        if (kt) __syncthreads();
        const float* ap = aptr + kt * 64;
        const unsigned short* bp = bptr + kt * 64;
        float4 a0 = ((const float4*)ap)[0], a1 = ((const float4*)ap)[1];
        float4 a2 = ((const float4*)ap)[2], a3 = ((const float4*)ap)[3];
        uint4 b0 = *(const uint4*)bp, b1 = *(const uint4*)(bp + 8);
        *(uint4*)(Asg + arow * 72 + acol)     = pack_q(a0, a1);
        *(uint4*)(Asg + arow * 72 + acol + 8) = pack_q(a2, a3);
        *(uint4*)(Bsg + arow * 72 + acol)     = b0;
        *(uint4*)(Bsg + arow * 72 + acol + 8) = b1;
        __syncthreads();

#pragma unroll
        for (int ks = 0; ks < 2; ++ks) {
            s8v a_frag[2], b_frag[2];
#pragma unroll
            for (int i = 0; i < 2; ++i)
                a_frag[i] = *(const s8v*)(Asg + (wave_m + 16 * i + lr) * 72 + ks * 32 + lq * 8);
#pragma unroll
            for (int j = 0; j < 2; ++j)
                b_frag[j] = *(const s8v*)(Bsg + (wave_n + 16 * j + lr) * 72 + ks * 32 + lq * 8);
#pragma unroll
            for (int i = 0; i < 2; ++i)
#pragma unroll
                for (int j = 0; j < 2; ++j)
                    acc[i][j] = __builtin_amdgcn_mfma_f32_16x16x32_bf16(
                        a_frag[i], b_frag[j], acc[i][j], 0, 0, 0);
        }
    }
    __syncthreads();

    // combine K-halves through the cs transpose buffer
    if (g == 0) {
#pragma unroll
        for (int i = 0; i < 2; ++i)
#pragma unroll
            for (int j = 0; j < 2; ++j)
#pragma unroll
                for (int reg = 0; reg < 4; ++reg)
                    cs[(wave_n + 16 * j + lr) * 68 + wave_m + 16 * i + lq * 4 + reg] = acc[i][j][reg];
    }
    __syncthreads();
    if (g == 1) {
#pragma unroll
        for (int i = 0; i < 2; ++i)
#pragma unroll
            for (int j = 0; j < 2; ++j)
#pragma unroll
                for (int reg = 0; reg < 4; ++reg)
                    cs[(wave_n + 16 * j + lr) * 68 + wave_m + 16 * i + lq * 4 + reg] += acc[i][j][reg];
    }
    __syncthreads();

    // coalesced stores + log-softmax partials (threads 0-255)
    if (tid < 256) {
        const int n = tid >> 2, q = tid & 3;
        const int v0 = bm * 64 + q * 16;
        float4 vals[4];
        float m_loc = -1e30f;
#pragma unroll
        for (int k = 0; k < 4; ++k) {
            float4 cv = *(const float4*)(cs + n * 68 + q * 16 + 4 * k);
            float4 bv = *(const float4*)(h2ob + v0 + 4 * k);
            cv.x += bv.x; cv.y += bv.y; cv.z += bv.z; cv.w += bv.w;
            vals[k] = cv;
            *(float4*)(dlogits + (size_t)n * V + v0 + 4 * k) = cv;
            m_loc = fmaxf(m_loc, fmaxf(fmaxf(cv.x, cv.y), fmaxf(cv.z, cv.w)));
        }
        float s_loc = 0.f;
#pragma unroll
        for (int k = 0; k < 4; ++k) {
            s_loc += __expf(vals[k].x - m_loc) + __expf(vals[k].y - m_loc)
                   + __expf(vals[k].z - m_loc) + __expf(vals[k].w - m_loc);
        }
        // combine the 4 q-lanes (adjacent lanes) of row n
        float m2 = fmaxf(m_loc, __shfl_xor(m_loc, 1, 64));
        m2 = fmaxf(m2, __shfl_xor(m2, 2, 64));
        s_loc *= __expf(m_loc - m2);
        float s2 = s_loc + __shfl_xor(s_loc, 1, 64);
        s2 += __shfl_xor(s2, 2, 64);
        if (q == 0) {
            pmax[(size_t)n * VT + bm] = m2;
            psum[(size_t)n * VT + bm] = s2;
        }
    }
}

// ---------------------------------------------------------------------------
// K4b: fused lse + normalize. grid (64 n, 8 chunks), block 256. Each block
// REDUNDANTLY reduces row n's 500 (pmax,psum) partials (~4 KB, L2-hot,
// trivial vs a second launch) then normalizes its 4000-float chunk of
// dlogits row n at full-GPU BW. Replaces k_lse + k_norm (one launch saved,
// identical reduction order per row -> bitwise-same lse as k_lse).
// ---------------------------------------------------------------------------
__global__ __launch_bounds__(256) void k_lse_norm(
    const float* __restrict__ pmax, const float* __restrict__ psum,
    float* __restrict__ dlogits)
{
    __shared__ float rm[4], rs[4];
    __shared__ float lsev;
    const int n = blockIdx.x, ch = blockIdx.y, t = threadIdx.x;
    float m0 = (t < VT) ? pmax[(size_t)n * VT + t] : -1e30f;
    float m1 = (t + 256 < VT) ? pmax[(size_t)n * VT + t + 256] : -1e30f;
    float mm = fmaxf(m0, m1);
#pragma unroll
    for (int off = 32; off > 0; off >>= 1) mm = fmaxf(mm, __shfl_xor(mm, off, 64));
    if ((t & 63) == 0) rm[t >> 6] = mm;
    __syncthreads();
    float m = fmaxf(fmaxf(rm[0], rm[1]), fmaxf(rm[2], rm[3]));

    float s = 0.f;
    if (t < VT)       s += psum[(size_t)n * VT + t] * __expf(m0 - m);
    if (t + 256 < VT) s += psum[(size_t)n * VT + t + 256] * __expf(m1 - m);
#pragma unroll
    for (int off = 32; off > 0; off >>= 1) s += __shfl_xor(s, off, 64);
    if ((t & 63) == 0) rs[t >> 6] = s;
    __syncthreads();
    if (t == 0) {
        float st = rs[0] + rs[1] + rs[2] + rs[3];
        lsev = m + __logf(st);
    }
    __syncthreads();
    const float lse = lsev;

    // normalize chunk ch of row n: 4000 floats = 1000 float4, 256 threads
    float4* row = (float4*)(dlogits + (size_t)n * V) + ch * 1000;
#pragma unroll 2
    for (int idx = t; idx < 1000; idx += 256) {
        float4 v = row[idx];
        v.x -= lse; v.y -= lse; v.z -= lse; v.w -= lse;
        row[idx] = v;
    }
}

// ---------------------------------------------------------------------------
extern "C" void kernel_launch(void* const* d_in, const int* in_sizes, int n_in,
                              void* d_out, int out_size, void* d_ws, size_t ws_size,
                              hipStream_t stream)
{
    const int* ids   = (const int*)d_in[0];
    const float* h   = (const float*)d_in[1];
    const float* c   = (const float*)d_in[2];
    const float* enc = (const float*)d_in[3];
    const unsigned char* mask = (const unsigned char*)d_in[4];
    const float* embW = (const float*)d_in[5];
    const float* w_ih = (const float*)d_in[6];
    const float* b_ih = (const float*)d_in[7];
    const float* w_hh = (const float*)d_in[8];
    const float* b_hh = (const float*)d_in[9];
    const float* Wh   = (const float*)d_in[10];
    const float* Ws   = (const float*)d_in[11];
    const float* av   = (const float*)d_in[12];
    const float* h2oW = (const float*)d_in[13];
    const float* h2ob = (const float*)d_in[14];

    float* out = (float*)d_out;
    float* ws = (float*)d_ws;
    // layout (floats):
    float* gates_p = ws;                          // 8*64*2048 = 1048576
    float* sproj   = ws + 1048576;                // 32768
    float* scorep  = ws + 1048576 + 32768;        // 65536
    unsigned short* xb = (unsigned short*)(ws + 1048576 + 32768 + 65536);  // 64x1024 bf16
    // pmax/psum overlay the gates_p region (dead after k_lstm_pw)
    float* pmax = ws;                             // 64*500 = 32000
    float* psum = ws + 32000;                     // 32000

    k_gates<<<dim3(32, 8), 256, 0, stream>>>(ids, h, embW, w_ih, w_hh, gates_p);
    k_lstm_pw<<<128, 256, 0, stream>>>(gates_p, b_ih, b_hh, c, out, xb);
    k_sproj<<<128, 256, 0, stream>>>(out, Wh, sproj);
    k_score_gemm<<<dim3(8, 128), 256, 0, stream>>>(enc, Ws, sproj, av, scorep);
    k_softmax_ctx<<<dim3(64, 4), 128, 0, stream>>>(scorep, mask, enc, xb);
    k_logits<<<VT, 512, 0, stream>>>(h2oW, xb, h2ob, out, pmax, psum);
    k_lse_norm<<<dim3(64, 8), 256, 0, stream>>>(pmax, psum, out);
}

// Round 5
// 334.481 us; speedup vs baseline: 1.0320x; 1.0320x over previous
//
#include <hip/hip_runtime.h>
#include <hip/hip_bf16.h>
#include <math.h>

#define V 32000
#define E 512
#define H 512
#define N 64
#define L 128
#define NV (N*V)
#define NH (N*H)
#define MTOT (N*L)   // 8192 rows of the score GEMM
#define VT 500       // v-tiles (of 64) in k_logits

typedef short  s8v  __attribute__((ext_vector_type(8)));   // 8 bf16 (4 VGPRs)
typedef float  f4v  __attribute__((ext_vector_type(4)));

__device__ __forceinline__ float sigf(float x) { return 1.0f / (1.0f + __expf(-x)); }

// fp32 -> bf16 round-to-nearest-even (scalar path, non-hot kernels)
__device__ __forceinline__ unsigned short f2bf(float f) {
    unsigned int u = __float_as_uint(f);
    unsigned int r = u + 0x7FFFu + ((u >> 16) & 1u);
    return (unsigned short)(r >> 16);
}

// pair fp32 -> packed 2xbf16, RNE; compiler emits v_cvt_pk_bf16_f32
__device__ __forceinline__ unsigned int cvt2bf(float x, float y) {
    __hip_bfloat162 h2 = __float22bfloat162_rn(make_float2(x, y));
    unsigned int r;
    __builtin_memcpy(&r, &h2, 4);
    return r;
}

// 8 fp32 -> 4 packed bf16 pairs (one 16B LDS store)
__device__ __forceinline__ uint4 pack_q(float4 lo, float4 hi) {
    uint4 q;
    q.x = cvt2bf(lo.x, lo.y); q.y = cvt2bf(lo.z, lo.w);
    q.z = cvt2bf(hi.x, hi.y); q.w = cvt2bf(hi.z, hi.w);
    return q;
}

// ---------------------------------------------------------------------------
// K1: LSTM gate GEMM, k-split partials. grid (32 j-tiles, 8 k-splits of 128),
// block 256 = 64 j-lanes x 4 n-groups(16 n). LDS 32 KB.  (R0-proven tiling:
// 1 w-row/lane streamed sequentially = L1-friendly; 16 broadcast LDS reads.)
// ---------------------------------------------------------------------------
__global__ __launch_bounds__(256) void k_gates(
    const int* __restrict__ ids, const float* __restrict__ hprev,
    const float* __restrict__ embW, const float* __restrict__ w_ih,
    const float* __restrict__ w_hh, float* __restrict__ gates_p)
{
    __shared__ __align__(16) float xs[64 * 128];  // 32 KB
    const int bx = blockIdx.x;   // j-tile
    const int ks = blockIdx.y;   // k-split (0..7): 0-3 emb, 4-7 h
    const int tid = threadIdx.x;
    const bool emb_part = (ks < 4);
    const int koff = (ks & 3) * 128;

    for (int i = tid; i < 64 * 32; i += 256) {
        int n = i >> 5, kk4 = i & 31;
        float4 x4;
        if (emb_part)
            x4 = ((const float4*)(embW + (size_t)ids[n] * E + koff))[kk4];
        else
            x4 = ((const float4*)(hprev + (size_t)n * H + koff))[kk4];
        ((float4*)xs)[n * 32 + kk4] = x4;
    }
    __syncthreads();

    const int jl = tid & 63;
    const int ng = tid >> 6;
    const int j = bx * 64 + jl;
    const int nb = ng * 16;
    const float* wrow = (emb_part ? w_ih : w_hh) + (size_t)j * 512 + koff;

    float acc[16];
#pragma unroll
    for (int i = 0; i < 16; ++i) acc[i] = 0.f;

    for (int e4 = 0; e4 < 32; ++e4) {
        float4 w4 = ((const float4*)wrow)[e4];
#pragma unroll
        for (int i = 0; i < 16; ++i) {
            float4 x4 = ((const float4*)xs)[(nb + i) * 32 + e4];  // wave-uniform broadcast
            acc[i] += w4.x * x4.x + w4.y * x4.y + w4.z * x4.z + w4.w * x4.w;
        }
    }
#pragma unroll
    for (int i = 0; i < 16; ++i)
        gates_p[(size_t)ks * (64 * 2048) + (size_t)(nb + i) * 2048 + j] = acc[i];
}

// ---------------------------------------------------------------------------
// K1b: combine partials + biases, LSTM pointwise.  (unchanged)
// ---------------------------------------------------------------------------
__global__ __launch_bounds__(256) void k_lstm_pw(
    const float* __restrict__ gates_p, const float* __restrict__ b_ih,
    const float* __restrict__ b_hh, const float* __restrict__ cprev,
    float* __restrict__ out, unsigned short* __restrict__ xb)
{
    int i = blockIdx.x * 256 + threadIdx.x;  // 0..32767
    if (i >= NH) return;
    int n = i >> 9, k = i & 511;
    float g[4];
#pragma unroll
    for (int q = 0; q < 4; ++q) {
        int j = q * 512 + k;
        float s = b_ih[j] + b_hh[j];
#pragma unroll
        for (int ks = 0; ks < 8; ++ks)
            s += gates_p[(size_t)ks * (64 * 2048) + (size_t)n * 2048 + j];
        g[q] = s;
    }
    float ig = sigf(g[0]), fg = sigf(g[1]), gg = tanhf(g[2]), og = sigf(g[3]);
    float ct = fg * cprev[i] + ig * gg;
    float ht = og * tanhf(ct);
    out[NV + i] = ht;
    out[NV + NH + i] = ct;
    xb[(size_t)n * 1024 + k] = f2bf(ht);
}

// ---------------------------------------------------------------------------
// K2a: sproj = h_t @ Wh.T  (64 x 512, K=512). grid 128, block 256. (unchanged)
// ---------------------------------------------------------------------------
__global__ __launch_bounds__(256) void k_sproj(
    const float* __restrict__ out, const float* __restrict__ Wh,
    float* __restrict__ sproj)
{
    __shared__ __align__(16) float xs[512];
    int n = blockIdx.x >> 1;
    int h = (blockIdx.x & 1) * 256 + threadIdx.x;
    const float* ht = out + NV + (size_t)n * 512;
    for (int i = threadIdx.x; i < 512; i += 256) xs[i] = ht[i];
    __syncthreads();
    const float* wrow = Wh + (size_t)h * 512;
    float acc = 0.f;
    for (int e4 = 0; e4 < 128; ++e4) {
        float4 w4 = ((const float4*)wrow)[e4];
        float4 x4 = ((const float4*)xs)[e4];
        acc += w4.x * x4.x + w4.y * x4.y + w4.z * x4.z + w4.w * x4.w;
    }
    sproj[(size_t)n * 512 + h] = acc;
}

// ---------------------------------------------------------------------------
// K2b: score GEMM via bf16 MFMA + fused tanh/v-dot epilogue. Grid RESTORED
// to (128 bm, 8 bh): linearized block = bm + 128*bh, and 128%8==0 means all
// 8 bh-blocks sharing enc tile bm land on the SAME XCD -> per-XCD L2 reuse
// of enc (R3's swap put them on 8 different XCDs = 8x refetch).
// ---------------------------------------------------------------------------
__global__ __launch_bounds__(256) void k_score_gemm(
    const float* __restrict__ enc, const float* __restrict__ Ws,
    const float* __restrict__ sproj, const float* __restrict__ av,
    float* __restrict__ scorep)
{
    __shared__ __align__(16) short As[64 * 72];
    __shared__ __align__(16) short Bs[64 * 72];
    __shared__ float sred[64];

    const int bm = blockIdx.x, bh = blockIdx.y;   // bm fastest-varying
    const int tid = threadIdx.x;
    const int w = tid >> 6, l = tid & 63;
    const int wave_m = (w >> 1) * 32, wave_h = (w & 1) * 32;
    const int lq = l >> 4, lr = l & 15;

    if (tid < 64) sred[tid] = 0.f;

    f4v acc[2][2];
#pragma unroll
    for (int i = 0; i < 2; ++i)
#pragma unroll
        for (int j = 0; j < 2; ++j) acc[i][j] = (f4v)0.f;

    for (int kt = 0; kt < 8; ++kt) {
        __syncthreads();
#pragma unroll
        for (int r = 0; r < 2; ++r) {
            int idx = (r * 256 + tid) * 8;
            int row = idx >> 6, col = idx & 63;
            const float* sa = enc + (size_t)(bm * 64 + row) * 512 + kt * 64 + col;
            const float* sb = Ws  + (size_t)(bh * 64 + row) * 512 + kt * 64 + col;
            float4 a0 = *(const float4*)sa, a1 = *(const float4*)(sa + 4);
            float4 b0 = *(const float4*)sb, b1 = *(const float4*)(sb + 4);
            *(uint4*)(As + row * 72 + col) = pack_q(a0, a1);
            *(uint4*)(Bs + row * 72 + col) = pack_q(b0, b1);
        }
        __syncthreads();

#pragma unroll
        for (int ks = 0; ks < 2; ++ks) {
            s8v a_frag[2], b_frag[2];
#pragma unroll
            for (int i = 0; i < 2; ++i)
                a_frag[i] = *(const s8v*)(As + (wave_m + 16 * i + lr) * 72 + ks * 32 + lq * 8);
#pragma unroll
            for (int j = 0; j < 2; ++j)
                b_frag[j] = *(const s8v*)(Bs + (wave_h + 16 * j + lr) * 72 + ks * 32 + lq * 8);
#pragma unroll
            for (int i = 0; i < 2; ++i)
#pragma unroll
                for (int j = 0; j < 2; ++j)
                    acc[i][j] = __builtin_amdgcn_mfma_f32_16x16x32_bf16(
                        a_frag[i], b_frag[j], acc[i][j], 0, 0, 0);
        }
    }
    __syncthreads();

    const int hc0 = bh * 64 + wave_h + lr;
#pragma unroll
    for (int i = 0; i < 2; ++i) {
#pragma unroll
        for (int reg = 0; reg < 4; ++reg) {
            int m_local = wave_m + 16 * i + lq * 4 + reg;
            int m = bm * 64 + m_local;
            int n = m >> 7;
            float p = 0.f;
#pragma unroll
            for (int j = 0; j < 2; ++j) {
                int hc = hc0 + 16 * j;
                float val = acc[i][j][reg] + sproj[(size_t)n * 512 + hc];
                p += tanhf(val) * av[hc];
            }
            p += __shfl_xor(p, 1, 64);
            p += __shfl_xor(p, 2, 64);
            p += __shfl_xor(p, 4, 64);
            p += __shfl_xor(p, 8, 64);
            if (lr == 0) atomicAdd(&sred[m_local], p);
        }
    }
    __syncthreads();
    if (tid < 64)
        scorep[(size_t)bh * MTOT + bm * 64 + tid] = sred[tid];
}

// ---------------------------------------------------------------------------
// K2c: combine score partials, mask, softmax over L, context. 4-way split
// over H. grid (64 n, 4 h-chunks), block 128.  (unchanged)
// ---------------------------------------------------------------------------
__global__ __launch_bounds__(128) void k_softmax_ctx(
    const float* __restrict__ scorep, const unsigned char* __restrict__ mask,
    const float* __restrict__ enc, unsigned short* __restrict__ xb)
{
    __shared__ float wl[128];
    __shared__ float red[4];
    const int n = blockIdx.x, hc = blockIdx.y, t = threadIdx.x;  // t = l index

    float s = 0.f;
#pragma unroll
    for (int q = 0; q < 8; ++q)
        s += scorep[(size_t)q * MTOT + n * 128 + t];
    if (mask[(size_t)n * 128 + t]) s = -1e30f;

    float m = s;
#pragma unroll
    for (int off = 32; off > 0; off >>= 1) m = fmaxf(m, __shfl_xor(m, off, 64));
    if ((t & 63) == 0) red[t >> 6] = m;
    __syncthreads();
    m = fmaxf(red[0], red[1]);
    float e = __expf(s - m);
    float ss = e;
#pragma unroll
    for (int off = 32; off > 0; off >>= 1) ss += __shfl_xor(ss, off, 64);
    if ((t & 63) == 0) red[2 + (t >> 6)] = ss;
    __syncthreads();
    float inv = 1.0f / (red[2] + red[3]);
    wl[t] = e * inv;
    __syncthreads();

    const float* encn = enc + (size_t)n * (L * H) + hc * 128 + t;
    float acc = 0.f;
#pragma unroll 8
    for (int ll = 0; ll < 128; ++ll)
        acc += wl[ll] * encn[(size_t)ll * 512];
    xb[(size_t)n * 1024 + 512 + hc * 128 + t] = f2bf(acc);
}

// ---------------------------------------------------------------------------
// K4a: logits GEMM via bf16 MFMA. (R3/R4 verbatim): 512 threads = 8 waves,
// in-block K-split (waves 0-3: K[0:512], waves 4-7: K[512:1024]), halves
// combined through the cs transpose buffer. Epilogue threads 0-255.
// ---------------------------------------------------------------------------
__global__ __launch_bounds__(512) void k_logits(
    const float* __restrict__ h2oW, const unsigned short* __restrict__ xb,
    const float* __restrict__ h2ob, float* __restrict__ dlogits,
    float* __restrict__ pmax, float* __restrict__ psum)
{
    __shared__ __align__(16) short As[2][64 * 72];   // 18432 B
    __shared__ __align__(16) short Bs[2][64 * 72];   // 18432 B
    __shared__ __align__(16) float cs[64 * 68];      // 17408 B

    const int bm = blockIdx.x;   // v-tile
    const int tid = threadIdx.x;
    const int g = tid >> 8;            // K-half (0 or 1)
    const int tl = tid & 255;          // index within group
    const int w2 = (tid >> 6) & 3;     // wave within group
    const int l = tid & 63;
    const int wave_m = (w2 & 1) * 32, wave_n = (w2 >> 1) * 32;
    const int lq = l >> 4, lr = l & 15;

    const int arow = tl >> 2;            // 0..63
    const int acol = (tl & 3) * 16;      // 0,16,32,48
    const float* aptr = h2oW + (size_t)(bm * 64 + arow) * 1024 + g * 512 + acol;
    const unsigned short* bptr = xb + (size_t)arow * 1024 + g * 512 + acol;

    short* Asg = As[g];
    short* Bsg = Bs[g];

    f4v acc[2][2];
#pragma unroll
    for (int i = 0; i < 2; ++i)
#pragma unroll
        for (int j = 0; j < 2; ++j) acc[i][j] = (f4v)0.f;

#pragma unroll 1
    for (int kt = 0; kt < 8; ++kt) {
        if (kt) __syncthreads();
        const float* ap = aptr + kt * 64;
        const unsigned short* bp = bptr + kt * 64;
        float4 a0 = ((const float4*)ap)[0], a1 = ((const float4*)ap)[1];
        float4 a2 = ((const float4*)ap)[2], a3 = ((const float4*)ap)[3];
        uint4 b0 = *(const uint4*)bp, b1 = *(const uint4*)(bp + 8);
        *(uint4*)(Asg + arow * 72 + acol)     = pack_q(a0, a1);
        *(uint4*)(Asg + arow * 72 + acol + 8) = pack_q(a2, a3);
        *(uint4*)(Bsg + arow * 72 + acol)     = b0;
        *(uint4*)(Bsg + arow * 72 + acol + 8) = b1;
        __syncthreads();

#pragma unroll
        for (int ks = 0; ks < 2; ++ks) {
            s8v a_frag[2], b_frag[2];
#pragma unroll
            for (int i = 0; i < 2; ++i)
                a_frag[i] = *(const s8v*)(Asg + (wave_m + 16 * i + lr) * 72 + ks * 32 + lq * 8);
#pragma unroll
            for (int j = 0; j < 2; ++j)
                b_frag[j] = *(const s8v*)(Bsg + (wave_n + 16 * j + lr) * 72 + ks * 32 + lq * 8);
#pragma unroll
            for (int i = 0; i < 2; ++i)
#pragma unroll
                for (int j = 0; j < 2; ++j)
                    acc[i][j] = __builtin_amdgcn_mfma_f32_16x16x32_bf16(
                        a_frag[i], b_frag[j], acc[i][j], 0, 0, 0);
        }
    }
    __syncthreads();

    // combine K-halves through the cs transpose buffer
    if (g == 0) {
#pragma unroll
        for (int i = 0; i < 2; ++i)
#pragma unroll
            for (int j = 0; j < 2; ++j)
#pragma unroll
                for (int reg = 0; reg < 4; ++reg)
                    cs[(wave_n + 16 * j + lr) * 68 + wave_m + 16 * i + lq * 4 + reg] = acc[i][j][reg];
    }
    __syncthreads();
    if (g == 1) {
#pragma unroll
        for (int i = 0; i < 2; ++i)
#pragma unroll
            for (int j = 0; j < 2; ++j)
#pragma unroll
                for (int reg = 0; reg < 4; ++reg)
                    cs[(wave_n + 16 * j + lr) * 68 + wave_m + 16 * i + lq * 4 + reg] += acc[i][j][reg];
    }
    __syncthreads();

    // coalesced stores + log-softmax partials (threads 0-255)
    if (tid < 256) {
        const int n = tid >> 2, q = tid & 3;
        const int v0 = bm * 64 + q * 16;
        float4 vals[4];
        float m_loc = -1e30f;
#pragma unroll
        for (int k = 0; k < 4; ++k) {
            float4 cv = *(const float4*)(cs + n * 68 + q * 16 + 4 * k);
            float4 bv = *(const float4*)(h2ob + v0 + 4 * k);
            cv.x += bv.x; cv.y += bv.y; cv.z += bv.z; cv.w += bv.w;
            vals[k] = cv;
            *(float4*)(dlogits + (size_t)n * V + v0 + 4 * k) = cv;
            m_loc = fmaxf(m_loc, fmaxf(fmaxf(cv.x, cv.y), fmaxf(cv.z, cv.w)));
        }
        float s_loc = 0.f;
#pragma unroll
        for (int k = 0; k < 4; ++k) {
            s_loc += __expf(vals[k].x - m_loc) + __expf(vals[k].y - m_loc)
                   + __expf(vals[k].z - m_loc) + __expf(vals[k].w - m_loc);
        }
        // combine the 4 q-lanes (adjacent lanes) of row n
        float m2 = fmaxf(m_loc, __shfl_xor(m_loc, 1, 64));
        m2 = fmaxf(m2, __shfl_xor(m2, 2, 64));
        s_loc *= __expf(m_loc - m2);
        float s2 = s_loc + __shfl_xor(s_loc, 1, 64);
        s2 += __shfl_xor(s2, 2, 64);
        if (q == 0) {
            pmax[(size_t)n * VT + bm] = m2;
            psum[(size_t)n * VT + bm] = s2;
        }
    }
}

// ---------------------------------------------------------------------------
// K4b: fused lse + normalize. grid (64 n, 8 chunks), block 256. Each block
// REDUNDANTLY reduces row n's 500 (pmax,psum) partials (~4 KB, L2-hot)
// then normalizes its 4000-float chunk of dlogits row n.  (R4 verbatim)
// ---------------------------------------------------------------------------
__global__ __launch_bounds__(256) void k_lse_norm(
    const float* __restrict__ pmax, const float* __restrict__ psum,
    float* __restrict__ dlogits)
{
    __shared__ float rm[4], rs[4];
    __shared__ float lsev;
    const int n = blockIdx.x, ch = blockIdx.y, t = threadIdx.x;
    float m0 = (t < VT) ? pmax[(size_t)n * VT + t] : -1e30f;
    float m1 = (t + 256 < VT) ? pmax[(size_t)n * VT + t + 256] : -1e30f;
    float mm = fmaxf(m0, m1);
#pragma unroll
    for (int off = 32; off > 0; off >>= 1) mm = fmaxf(mm, __shfl_xor(mm, off, 64));
    if ((t & 63) == 0) rm[t >> 6] = mm;
    __syncthreads();
    float m = fmaxf(fmaxf(rm[0], rm[1]), fmaxf(rm[2], rm[3]));

    float s = 0.f;
    if (t < VT)       s += psum[(size_t)n * VT + t] * __expf(m0 - m);
    if (t + 256 < VT) s += psum[(size_t)n * VT + t + 256] * __expf(m1 - m);
#pragma unroll
    for (int off = 32; off > 0; off >>= 1) s += __shfl_xor(s, off, 64);
    if ((t & 63) == 0) rs[t >> 6] = s;
    __syncthreads();
    if (t == 0) {
        float st = rs[0] + rs[1] + rs[2] + rs[3];
        lsev = m + __logf(st);
    }
    __syncthreads();
    const float lse = lsev;

    // normalize chunk ch of row n: 4000 floats = 1000 float4, 256 threads
    float4* row = (float4*)(dlogits + (size_t)n * V) + ch * 1000;
#pragma unroll 2
    for (int idx = t; idx < 1000; idx += 256) {
        float4 v = row[idx];
        v.x -= lse; v.y -= lse; v.z -= lse; v.w -= lse;
        row[idx] = v;
    }
}

// ---------------------------------------------------------------------------
extern "C" void kernel_launch(void* const* d_in, const int* in_sizes, int n_in,
                              void* d_out, int out_size, void* d_ws, size_t ws_size,
                              hipStream_t stream)
{
    const int* ids   = (const int*)d_in[0];
    const float* h   = (const float*)d_in[1];
    const float* c   = (const float*)d_in[2];
    const float* enc = (const float*)d_in[3];
    const unsigned char* mask = (const unsigned char*)d_in[4];
    const float* embW = (const float*)d_in[5];
    const float* w_ih = (const float*)d_in[6];
    const float* b_ih = (const float*)d_in[7];
    const float* w_hh = (const float*)d_in[8];
    const float* b_hh = (const float*)d_in[9];
    const float* Wh   = (const float*)d_in[10];
    const float* Ws   = (const float*)d_in[11];
    const float* av   = (const float*)d_in[12];
    const float* h2oW = (const float*)d_in[13];
    const float* h2ob = (const float*)d_in[14];

    float* out = (float*)d_out;
    float* ws = (float*)d_ws;
    // layout (floats):
    float* gates_p = ws;                          // 8*64*2048 = 1048576
    float* sproj   = ws + 1048576;                // 32768
    float* scorep  = ws + 1048576 + 32768;        // 65536
    unsigned short* xb = (unsigned short*)(ws + 1048576 + 32768 + 65536);  // 64x1024 bf16
    // pmax/psum overlay the gates_p region (dead after k_lstm_pw)
    float* pmax = ws;                             // 64*500 = 32000
    float* psum = ws + 32000;                     // 32000

    k_gates<<<dim3(32, 8), 256, 0, stream>>>(ids, h, embW, w_ih, w_hh, gates_p);
    k_lstm_pw<<<128, 256, 0, stream>>>(gates_p, b_ih, b_hh, c, out, xb);
    k_sproj<<<128, 256, 0, stream>>>(out, Wh, sproj);
    k_score_gemm<<<dim3(128, 8), 256, 0, stream>>>(enc, Ws, sproj, av, scorep);
    k_softmax_ctx<<<dim3(64, 4), 128, 0, stream>>>(scorep, mask, enc, xb);
    k_logits<<<VT, 512, 0, stream>>>(h2oW, xb, h2ob, out, pmax, psum);
    k_lse_norm<<<dim3(64, 8), 256, 0, stream>>>(pmax, psum, out);
}

// Round 6
// 320.987 us; speedup vs baseline: 1.0754x; 1.0420x over previous
//
#include <hip/hip_runtime.h>
#include <hip/hip_bf16.h>
#include <math.h>

#define V 32000
#define E 512
#define H 512
#define N 64
#define L 128
#define NV (N*V)
#define NH (N*H)
#define MTOT (N*L)   // 8192 rows of the score GEMM
#define VT 500       // v-tiles (of 64) in k_logits

typedef short  s8v  __attribute__((ext_vector_type(8)));   // 8 bf16 (4 VGPRs)
typedef float  f4v  __attribute__((ext_vector_type(4)));

__device__ __forceinline__ float sigf(float x) { return 1.0f / (1.0f + __expf(-x)); }

// fp32 -> bf16 round-to-nearest-even (scalar path, non-hot kernels)
__device__ __forceinline__ unsigned short f2bf(float f) {
    unsigned int u = __float_as_uint(f);
    unsigned int r = u + 0x7FFFu + ((u >> 16) & 1u);
    return (unsigned short)(r >> 16);
}

// pair fp32 -> packed 2xbf16, RNE; compiler emits v_cvt_pk_bf16_f32
__device__ __forceinline__ unsigned int cvt2bf(float x, float y) {
    __hip_bfloat162 h2 = __float22bfloat162_rn(make_float2(x, y));
    unsigned int r;
    __builtin_memcpy(&r, &h2, 4);
    return r;
}

// 8 fp32 -> 4 packed bf16 pairs (one 16B LDS store)
__device__ __forceinline__ uint4 pack_q(float4 lo, float4 hi) {
    uint4 q;
    q.x = cvt2bf(lo.x, lo.y); q.y = cvt2bf(lo.z, lo.w);
    q.z = cvt2bf(hi.x, hi.y); q.w = cvt2bf(hi.z, hi.w);
    return q;
}

// ---------------------------------------------------------------------------
// K1: LSTM gate GEMM, k-split partials. grid (32 j-tiles, 8 k-splits of 128),
// block 512 = 64 j-lanes x 8 n-groups(8 n). Same staging/traffic as the
// proven 256-thr version, but 8 waves/block -> 2 waves/SIMD so ds_read->FMA
// dependency stalls overlap across waves (was 1 wave/SIMD = fully exposed).
// ---------------------------------------------------------------------------
__global__ __launch_bounds__(512) void k_gates(
    const int* __restrict__ ids, const float* __restrict__ hprev,
    const float* __restrict__ embW, const float* __restrict__ w_ih,
    const float* __restrict__ w_hh, float* __restrict__ gates_p)
{
    __shared__ __align__(16) float xs[64 * 128];  // 32 KB
    const int bx = blockIdx.x;   // j-tile
    const int ks = blockIdx.y;   // k-split (0..7): 0-3 emb, 4-7 h
    const int tid = threadIdx.x;
    const bool emb_part = (ks < 4);
    const int koff = (ks & 3) * 128;

    for (int i = tid; i < 64 * 32; i += 512) {
        int n = i >> 5, kk4 = i & 31;
        float4 x4;
        if (emb_part)
            x4 = ((const float4*)(embW + (size_t)ids[n] * E + koff))[kk4];
        else
            x4 = ((const float4*)(hprev + (size_t)n * H + koff))[kk4];
        ((float4*)xs)[n * 32 + kk4] = x4;
    }
    __syncthreads();

    const int jl = tid & 63;
    const int ng = tid >> 6;          // 0..7
    const int j = bx * 64 + jl;
    const int nb = ng * 8;
    const float* wrow = (emb_part ? w_ih : w_hh) + (size_t)j * 512 + koff;

    float acc[8];
#pragma unroll
    for (int i = 0; i < 8; ++i) acc[i] = 0.f;

    for (int e4 = 0; e4 < 32; ++e4) {
        float4 w4 = ((const float4*)wrow)[e4];
#pragma unroll
        for (int i = 0; i < 8; ++i) {
            float4 x4 = ((const float4*)xs)[(nb + i) * 32 + e4];  // wave-uniform broadcast
            acc[i] += w4.x * x4.x + w4.y * x4.y + w4.z * x4.z + w4.w * x4.w;
        }
    }
#pragma unroll
    for (int i = 0; i < 8; ++i)
        gates_p[(size_t)ks * (64 * 2048) + (size_t)(nb + i) * 2048 + j] = acc[i];
}

// ---------------------------------------------------------------------------
// K1b: combine partials + biases, LSTM pointwise. grid 256 x 128 (1 block/CU
// spread for the latency-bound strided partial reads).
// ---------------------------------------------------------------------------
__global__ __launch_bounds__(128) void k_lstm_pw(
    const float* __restrict__ gates_p, const float* __restrict__ b_ih,
    const float* __restrict__ b_hh, const float* __restrict__ cprev,
    float* __restrict__ out, unsigned short* __restrict__ xb)
{
    int i = blockIdx.x * 128 + threadIdx.x;  // 0..32767
    if (i >= NH) return;
    int n = i >> 9, k = i & 511;
    float g[4];
#pragma unroll
    for (int q = 0; q < 4; ++q) {
        int j = q * 512 + k;
        float s = b_ih[j] + b_hh[j];
#pragma unroll
        for (int ks = 0; ks < 8; ++ks)
            s += gates_p[(size_t)ks * (64 * 2048) + (size_t)n * 2048 + j];
        g[q] = s;
    }
    float ig = sigf(g[0]), fg = sigf(g[1]), gg = tanhf(g[2]), og = sigf(g[3]);
    float ct = fg * cprev[i] + ig * gg;
    float ht = og * tanhf(ct);
    out[NV + i] = ht;
    out[NV + NH + i] = ct;
    xb[(size_t)n * 1024 + k] = f2bf(ht);
}

// ---------------------------------------------------------------------------
// K2: score GEMM via bf16 MFMA with sproj FUSED via K-extension.
// tanh-arg[m][h] = sum_k enc[m][k]*Ws[h][k]  +  sum_k h_t[n][k]*Wh[h][k]
// (n = bm>>1 is constant per 64-row m-tile). Phase 1 (kt 0..7): A=enc tile,
// B=Ws tile. Phase 2 (kt 0..7): A = xb[n][0:512] bf16 h_t broadcast to all
// 64 rows, B = Wh tile. One MFMA accumulator; epilogue drops the sproj read.
// k_sproj launch eliminated. Grid (128 bm, 8 bh) -- bm fastest: the 8
// bh-sharers of an enc tile stay on one XCD (128%8==0, R5-proven).
// ---------------------------------------------------------------------------
__global__ __launch_bounds__(256) void k_score_gemm(
    const float* __restrict__ enc, const float* __restrict__ Ws,
    const float* __restrict__ Wh, const unsigned short* __restrict__ xb,
    const float* __restrict__ av, float* __restrict__ scorep)
{
    __shared__ __align__(16) short As[64 * 72];
    __shared__ __align__(16) short Bs[64 * 72];
    __shared__ float sred[64];

    const int bm = blockIdx.x, bh = blockIdx.y;   // bm fastest-varying
    const int tid = threadIdx.x;
    const int w = tid >> 6, l = tid & 63;
    const int wave_m = (w >> 1) * 32, wave_h = (w & 1) * 32;
    const int lq = l >> 4, lr = l & 15;
    const int n = bm >> 1;            // batch row for this m-tile (constant)

    if (tid < 64) sred[tid] = 0.f;

    f4v acc[2][2];
#pragma unroll
    for (int i = 0; i < 2; ++i)
#pragma unroll
        for (int j = 0; j < 2; ++j) acc[i][j] = (f4v)0.f;

#define MFMA_PHASE()                                                       \
    {                                                                      \
        _Pragma("unroll")                                                  \
        for (int ks = 0; ks < 2; ++ks) {                                   \
            s8v a_frag[2], b_frag[2];                                      \
            _Pragma("unroll")                                              \
            for (int i = 0; i < 2; ++i)                                    \
                a_frag[i] = *(const s8v*)(As + (wave_m + 16 * i + lr) * 72 + ks * 32 + lq * 8); \
            _Pragma("unroll")                                              \
            for (int j = 0; j < 2; ++j)                                    \
                b_frag[j] = *(const s8v*)(Bs + (wave_h + 16 * j + lr) * 72 + ks * 32 + lq * 8); \
            _Pragma("unroll")                                              \
            for (int i = 0; i < 2; ++i)                                    \
                _Pragma("unroll")                                          \
                for (int j = 0; j < 2; ++j)                                \
                    acc[i][j] = __builtin_amdgcn_mfma_f32_16x16x32_bf16(   \
                        a_frag[i], b_frag[j], acc[i][j], 0, 0, 0);         \
        }                                                                  \
    }

    // ---- phase 1: enc x Ws (K = 0..511) ----
    for (int kt = 0; kt < 8; ++kt) {
        __syncthreads();
#pragma unroll
        for (int r = 0; r < 2; ++r) {
            int idx = (r * 256 + tid) * 8;
            int row = idx >> 6, col = idx & 63;
            const float* sa = enc + (size_t)(bm * 64 + row) * 512 + kt * 64 + col;
            const float* sb = Ws  + (size_t)(bh * 64 + row) * 512 + kt * 64 + col;
            float4 a0 = *(const float4*)sa, a1 = *(const float4*)(sa + 4);
            float4 b0 = *(const float4*)sb, b1 = *(const float4*)(sb + 4);
            *(uint4*)(As + row * 72 + col) = pack_q(a0, a1);
            *(uint4*)(Bs + row * 72 + col) = pack_q(b0, b1);
        }
        __syncthreads();
        MFMA_PHASE();
    }

    // ---- phase 2: h_t x Wh (sproj, K-extension) ----
    for (int kt = 0; kt < 8; ++kt) {
        __syncthreads();
#pragma unroll
        for (int r = 0; r < 2; ++r) {
            int idx = (r * 256 + tid) * 8;
            int row = idx >> 6, col = idx & 63;
            // A: same h_t slice for every row (L1 broadcast), already bf16
            uint4 ha = *(const uint4*)(xb + (size_t)n * 1024 + kt * 64 + col);
            const float* sb = Wh + (size_t)(bh * 64 + row) * 512 + kt * 64 + col;
            float4 b0 = *(const float4*)sb, b1 = *(const float4*)(sb + 4);
            *(uint4*)(As + row * 72 + col) = ha;
            *(uint4*)(Bs + row * 72 + col) = pack_q(b0, b1);
        }
        __syncthreads();
        MFMA_PHASE();
    }
#undef MFMA_PHASE
    __syncthreads();

    const int hc0 = bh * 64 + wave_h + lr;
#pragma unroll
    for (int i = 0; i < 2; ++i) {
#pragma unroll
        for (int reg = 0; reg < 4; ++reg) {
            int m_local = wave_m + 16 * i + lq * 4 + reg;
            float p = 0.f;
#pragma unroll
            for (int j = 0; j < 2; ++j) {
                int hc = hc0 + 16 * j;
                p += tanhf(acc[i][j][reg]) * av[hc];
            }
            p += __shfl_xor(p, 1, 64);
            p += __shfl_xor(p, 2, 64);
            p += __shfl_xor(p, 4, 64);
            p += __shfl_xor(p, 8, 64);
            if (lr == 0) atomicAdd(&sred[m_local], p);
        }
    }
    __syncthreads();
    if (tid < 64)
        scorep[(size_t)bh * MTOT + bm * 64 + tid] = sred[tid];
}

// ---------------------------------------------------------------------------
// K2c: combine score partials, mask, softmax over L, context. 4-way split
// over H. grid (64 n, 4 h-chunks), block 128.  (unchanged)
// ---------------------------------------------------------------------------
__global__ __launch_bounds__(128) void k_softmax_ctx(
    const float* __restrict__ scorep, const unsigned char* __restrict__ mask,
    const float* __restrict__ enc, unsigned short* __restrict__ xb)
{
    __shared__ float wl[128];
    __shared__ float red[4];
    const int n = blockIdx.x, hc = blockIdx.y, t = threadIdx.x;  // t = l index

    float s = 0.f;
#pragma unroll
    for (int q = 0; q < 8; ++q)
        s += scorep[(size_t)q * MTOT + n * 128 + t];
    if (mask[(size_t)n * 128 + t]) s = -1e30f;

    float m = s;
#pragma unroll
    for (int off = 32; off > 0; off >>= 1) m = fmaxf(m, __shfl_xor(m, off, 64));
    if ((t & 63) == 0) red[t >> 6] = m;
    __syncthreads();
    m = fmaxf(red[0], red[1]);
    float e = __expf(s - m);
    float ss = e;
#pragma unroll
    for (int off = 32; off > 0; off >>= 1) ss += __shfl_xor(ss, off, 64);
    if ((t & 63) == 0) red[2 + (t >> 6)] = ss;
    __syncthreads();
    float inv = 1.0f / (red[2] + red[3]);
    wl[t] = e * inv;
    __syncthreads();

    const float* encn = enc + (size_t)n * (L * H) + hc * 128 + t;
    float acc = 0.f;
#pragma unroll 8
    for (int ll = 0; ll < 128; ++ll)
        acc += wl[ll] * encn[(size_t)ll * 512];
    xb[(size_t)n * 1024 + 512 + hc * 128 + t] = f2bf(acc);
}

// ---------------------------------------------------------------------------
// K4a: logits GEMM via bf16 MFMA. (R3/R5 verbatim): 512 threads = 8 waves,
// in-block K-split (waves 0-3: K[0:512], waves 4-7: K[512:1024]), halves
// combined through the cs transpose buffer. Epilogue threads 0-255.
// ---------------------------------------------------------------------------
__global__ __launch_bounds__(512) void k_logits(
    const float* __restrict__ h2oW, const unsigned short* __restrict__ xb,
    const float* __restrict__ h2ob, float* __restrict__ dlogits,
    float* __restrict__ pmax, float* __restrict__ psum)
{
    __shared__ __align__(16) short As[2][64 * 72];   // 18432 B
    __shared__ __align__(16) short Bs[2][64 * 72];   // 18432 B
    __shared__ __align__(16) float cs[64 * 68];      // 17408 B

    const int bm = blockIdx.x;   // v-tile
    const int tid = threadIdx.x;
    const int g = tid >> 8;            // K-half (0 or 1)
    const int tl = tid & 255;          // index within group
    const int w2 = (tid >> 6) & 3;     // wave within group
    const int l = tid & 63;
    const int wave_m = (w2 & 1) * 32, wave_n = (w2 >> 1) * 32;
    const int lq = l >> 4, lr = l & 15;

    const int arow = tl >> 2;            // 0..63
    const int acol = (tl & 3) * 16;      // 0,16,32,48
    const float* aptr = h2oW + (size_t)(bm * 64 + arow) * 1024 + g * 512 + acol;
    const unsigned short* bptr = xb + (size_t)arow * 1024 + g * 512 + acol;

    short* Asg = As[g];
    short* Bsg = Bs[g];

    f4v acc[2][2];
#pragma unroll
    for (int i = 0; i < 2; ++i)
#pragma unroll
        for (int j = 0; j < 2; ++j) acc[i][j] = (f4v)0.f;

#pragma unroll 1
    for (int kt = 0; kt < 8; ++kt) {
        if (kt) __syncthreads();
        const float* ap = aptr + kt * 64;
        const unsigned short* bp = bptr + kt * 64;
        float4 a0 = ((const float4*)ap)[0], a1 = ((const float4*)ap)[1];
        float4 a2 = ((const float4*)ap)[2], a3 = ((const float4*)ap)[3];
        uint4 b0 = *(const uint4*)bp, b1 = *(const uint4*)(bp + 8);
        *(uint4*)(Asg + arow * 72 + acol)     = pack_q(a0, a1);
        *(uint4*)(Asg + arow * 72 + acol + 8) = pack_q(a2, a3);
        *(uint4*)(Bsg + arow * 72 + acol)     = b0;
        *(uint4*)(Bsg + arow * 72 + acol + 8) = b1;
        __syncthreads();

#pragma unroll
        for (int ks = 0; ks < 2; ++ks) {
            s8v a_frag[2], b_frag[2];
#pragma unroll
            for (int i = 0; i < 2; ++i)
                a_frag[i] = *(const s8v*)(Asg + (wave_m + 16 * i + lr) * 72 + ks * 32 + lq * 8);
#pragma unroll
            for (int j = 0; j < 2; ++j)
                b_frag[j] = *(const s8v*)(Bsg + (wave_n + 16 * j + lr) * 72 + ks * 32 + lq * 8);
#pragma unroll
            for (int i = 0; i < 2; ++i)
#pragma unroll
                for (int j = 0; j < 2; ++j)
                    acc[i][j] = __builtin_amdgcn_mfma_f32_16x16x32_bf16(
                        a_frag[i], b_frag[j], acc[i][j], 0, 0, 0);
        }
    }
    __syncthreads();

    // combine K-halves through the cs transpose buffer
    if (g == 0) {
#pragma unroll
        for (int i = 0; i < 2; ++i)
#pragma unroll
            for (int j = 0; j < 2; ++j)
#pragma unroll
                for (int reg = 0; reg < 4; ++reg)
                    cs[(wave_n + 16 * j + lr) * 68 + wave_m + 16 * i + lq * 4 + reg] = acc[i][j][reg];
    }
    __syncthreads();
    if (g == 1) {
#pragma unroll
        for (int i = 0; i < 2; ++i)
#pragma unroll
            for (int j = 0; j < 2; ++j)
#pragma unroll
                for (int reg = 0; reg < 4; ++reg)
                    cs[(wave_n + 16 * j + lr) * 68 + wave_m + 16 * i + lq * 4 + reg] += acc[i][j][reg];
    }
    __syncthreads();

    // coalesced stores + log-softmax partials (threads 0-255)
    if (tid < 256) {
        const int n = tid >> 2, q = tid & 3;
        const int v0 = bm * 64 + q * 16;
        float4 vals[4];
        float m_loc = -1e30f;
#pragma unroll
        for (int k = 0; k < 4; ++k) {
            float4 cv = *(const float4*)(cs + n * 68 + q * 16 + 4 * k);
            float4 bv = *(const float4*)(h2ob + v0 + 4 * k);
            cv.x += bv.x; cv.y += bv.y; cv.z += bv.z; cv.w += bv.w;
            vals[k] = cv;
            *(float4*)(dlogits + (size_t)n * V + v0 + 4 * k) = cv;
            m_loc = fmaxf(m_loc, fmaxf(fmaxf(cv.x, cv.y), fmaxf(cv.z, cv.w)));
        }
        float s_loc = 0.f;
#pragma unroll
        for (int k = 0; k < 4; ++k) {
            s_loc += __expf(vals[k].x - m_loc) + __expf(vals[k].y - m_loc)
                   + __expf(vals[k].z - m_loc) + __expf(vals[k].w - m_loc);
        }
        // combine the 4 q-lanes (adjacent lanes) of row n
        float m2 = fmaxf(m_loc, __shfl_xor(m_loc, 1, 64));
        m2 = fmaxf(m2, __shfl_xor(m2, 2, 64));
        s_loc *= __expf(m_loc - m2);
        float s2 = s_loc + __shfl_xor(s_loc, 1, 64);
        s2 += __shfl_xor(s2, 2, 64);
        if (q == 0) {
            pmax[(size_t)n * VT + bm] = m2;
            psum[(size_t)n * VT + bm] = s2;
        }
    }
}

// ---------------------------------------------------------------------------
// K4b: fused lse + normalize. grid (64 n, 8 chunks), block 256.  (unchanged)
// ---------------------------------------------------------------------------
__global__ __launch_bounds__(256) void k_lse_norm(
    const float* __restrict__ pmax, const float* __restrict__ psum,
    float* __restrict__ dlogits)
{
    __shared__ float rm[4], rs[4];
    __shared__ float lsev;
    const int n = blockIdx.x, ch = blockIdx.y, t = threadIdx.x;
    float m0 = (t < VT) ? pmax[(size_t)n * VT + t] : -1e30f;
    float m1 = (t + 256 < VT) ? pmax[(size_t)n * VT + t + 256] : -1e30f;
    float mm = fmaxf(m0, m1);
#pragma unroll
    for (int off = 32; off > 0; off >>= 1) mm = fmaxf(mm, __shfl_xor(mm, off, 64));
    if ((t & 63) == 0) rm[t >> 6] = mm;
    __syncthreads();
    float m = fmaxf(fmaxf(rm[0], rm[1]), fmaxf(rm[2], rm[3]));

    float s = 0.f;
    if (t < VT)       s += psum[(size_t)n * VT + t] * __expf(m0 - m);
    if (t + 256 < VT) s += psum[(size_t)n * VT + t + 256] * __expf(m1 - m);
#pragma unroll
    for (int off = 32; off > 0; off >>= 1) s += __shfl_xor(s, off, 64);
    if ((t & 63) == 0) rs[t >> 6] = s;
    __syncthreads();
    if (t == 0) {
        float st = rs[0] + rs[1] + rs[2] + rs[3];
        lsev = m + __logf(st);
    }
    __syncthreads();
    const float lse = lsev;

    // normalize chunk ch of row n: 4000 floats = 1000 float4, 256 threads
    float4* row = (float4*)(dlogits + (size_t)n * V) + ch * 1000;
#pragma unroll 2
    for (int idx = t; idx < 1000; idx += 256) {
        float4 v = row[idx];
        v.x -= lse; v.y -= lse; v.z -= lse; v.w -= lse;
        row[idx] = v;
    }
}

// ---------------------------------------------------------------------------
extern "C" void kernel_launch(void* const* d_in, const int* in_sizes, int n_in,
                              void* d_out, int out_size, void* d_ws, size_t ws_size,
                              hipStream_t stream)
{
    const int* ids   = (const int*)d_in[0];
    const float* h   = (const float*)d_in[1];
    const float* c   = (const float*)d_in[2];
    const float* enc = (const float*)d_in[3];
    const unsigned char* mask = (const unsigned char*)d_in[4];
    const float* embW = (const float*)d_in[5];
    const float* w_ih = (const float*)d_in[6];
    const float* b_ih = (const float*)d_in[7];
    const float* w_hh = (const float*)d_in[8];
    const float* b_hh = (const float*)d_in[9];
    const float* Wh   = (const float*)d_in[10];
    const float* Ws   = (const float*)d_in[11];
    const float* av   = (const float*)d_in[12];
    const float* h2oW = (const float*)d_in[13];
    const float* h2ob = (const float*)d_in[14];

    float* out = (float*)d_out;
    float* ws = (float*)d_ws;
    // layout (floats):
    float* gates_p = ws;                          // 8*64*2048 = 1048576
    float* scorep  = ws + 1048576 + 32768;        // 65536 (sproj slot retired)
    unsigned short* xb = (unsigned short*)(ws + 1048576 + 32768 + 65536);  // 64x1024 bf16
    // pmax/psum overlay the gates_p region (dead after k_lstm_pw)
    float* pmax = ws;                             // 64*500 = 32000
    float* psum = ws + 32000;                     // 32000

    k_gates<<<dim3(32, 8), 512, 0, stream>>>(ids, h, embW, w_ih, w_hh, gates_p);
    k_lstm_pw<<<256, 128, 0, stream>>>(gates_p, b_ih, b_hh, c, out, xb);
    k_score_gemm<<<dim3(128, 8), 256, 0, stream>>>(enc, Ws, Wh, xb, av, scorep);
    k_softmax_ctx<<<dim3(64, 4), 128, 0, stream>>>(scorep, mask, enc, xb);
    k_logits<<<VT, 512, 0, stream>>>(h2oW, xb, h2ob, out, pmax, psum);
    k_lse_norm<<<dim3(64, 8), 256, 0, stream>>>(pmax, psum, out);
}